// Round 18
// baseline (175.252 us; speedup 1.0000x reference)
//
#include <hip/hip_runtime.h>
#include <hip/hip_bf16.h>
#include <math.h>

#define B_    16
#define CI_   256
#define CO_   256
#define H_    64
#define W_    64
#define WDIM_ 512
#define NF_   16
#define FD_   512

typedef short bf16x8 __attribute__((ext_vector_type(8)));
typedef short s16x8  __attribute__((ext_vector_type(8)));
typedef float f32x4  __attribute__((ext_vector_type(4)));

__device__ __forceinline__ short f2bf(float f) {
  union { float f; unsigned u; } x; x.f = f;
  unsigned r = (x.u + 0x7FFFu + ((x.u >> 16) & 1u)) >> 16;
  return (short)r;
}
__device__ __forceinline__ float bf2f(short s) {
  union { unsigned u; float f; } x; x.u = ((unsigned)(unsigned short)s) << 16;
  return x.f;
}

__device__ __forceinline__ void gload16(const short* g, short* l) {
  __builtin_amdgcn_global_load_lds(
      (const __attribute__((address_space(1))) void*)g,
      (__attribute__((address_space(3))) void*)l, 16, 0, 0);
}

// Slice-major global layouts (elements):
//   kbf: [b][kb 4][cc 8][t 9][o 256][e 8]   kb-stride 147456, cc-stride 18432
//   xt : [b][kb 4][cc 8][hp 66][wp 66][e 8] cc-stride 34848
__device__ __forceinline__ size_t koff(int b, int kb, int cc, int t, int o) {
  return ((((((size_t)b * 4 + kb) * 8 + cc) * 9 + t) * 256) + o) * 8;
}
__device__ __forceinline__ size_t xoff(int b, int kb, int cc, int hp, int wp) {
  return ((((((size_t)b * 4 + kb) * 8 + cc) * 66 + hp) * 66) + wp) * 8;
}

// ---------------------------------------------------------------- prep: affine + out_linear->bf16
__global__ __launch_bounds__(256) void prep_kernel(
    const float* __restrict__ temb, const float* __restrict__ affine_w,
    const float* __restrict__ affine_b, const float* __restrict__ out_linear,
    float* __restrict__ s_ws, short* __restrict__ olbf) {
  int tid = threadIdx.x;
  if (blockIdx.x == 0) {
    int b = tid >> 4, k = tid & 15;
    const float* t = temb + b * WDIM_;
    const float* w = affine_w + k * WDIM_;
    float acc = 0.f;
    for (int j = 0; j < WDIM_; j += 4) {
      float4 tv = *(const float4*)(t + j);
      float4 wv = *(const float4*)(w + j);
      acc += tv.x * wv.x + tv.y * wv.y + tv.z * wv.z + tv.w * wv.w;
    }
    const float WGAIN = 6.9053399e-4f;  // (1/64)/sqrt(512)
    const float LRM   = 1.0f / 64.0f;
    s_ws[tid] = acc * WGAIN + affine_b[k] * LRM;
  } else {
    int e = (blockIdx.x - 1) * 256 + tid;   // vec8 index, 16384 total
    const float* src = out_linear + (size_t)e * 8;
    s16x8 pk;
#pragma unroll
    for (int j = 0; j < 8; ++j) pk[j] = f2bf(src[j]);
    *(s16x8*)(olbf + (size_t)e * 8) = pk;
  }
}

// ---------------------------------------------------------------- mag mix (per-i blocks)
__global__ __launch_bounds__(256) void magmix_kernel(
    const float* __restrict__ magnitude, const float* __restrict__ s_ws,
    short* __restrict__ mag_bf) {
  int bid = blockIdx.x;
  int i = bid >> 1;
  int f = ((bid & 1) << 8) + threadIdx.x;
  __shared__ float ssh[256];
  ssh[threadIdx.x] = s_ws[threadIdx.x];
  __syncthreads();
  float mg[16];
#pragma unroll
  for (int k = 0; k < 16; ++k)
    mg[k] = magnitude[(size_t)(k * CI_ + i) * FD_ + f];
#pragma unroll
  for (int b = 0; b < 16; ++b) {
    float acc = 0.f;
#pragma unroll
    for (int k = 0; k < 16; ++k) acc += mg[k] * ssh[b * 16 + k];
    mag_bf[(size_t)(b * CI_ + i) * FD_ + f] = f2bf(acc * 0.25f);
  }
}

// ---------------------------------------------------------------- fused kernsynth (MFMA) + xpose (HBM)
__global__ __launch_bounds__(512) void synth_xpose_kernel(
    const float* __restrict__ basis, const short* __restrict__ mag_bf,
    const short* __restrict__ olbf, short* __restrict__ kbf,
    const float* __restrict__ x, short* __restrict__ xt) {
  __shared__ short smem_s[24576];   // 48 KB union
  int tid = threadIdx.x;

  if (blockIdx.x < 288) {
    // ================= kernsynth =================
    short* alds = smem_s;           // [i 128][f 64] swizzled, 16 KB
    short* blds = smem_s + 8192;    // [o 256][f 64] swizzled, 32 KB
    int bid = blockIdx.x;
    int b  = bid / 18;
    int mt = bid - b * 18;
    int t   = mt >> 1;
    int i0g = (mt & 1) * 128;

    int lane = tid & 63;
    int wv = tid >> 6;
    int wm = wv >> 2, wn = wv & 3;
    int l15 = lane & 15, kb = lane >> 4;

    f32x4 acc[4][4];
#pragma unroll
    for (int m = 0; m < 4; ++m)
#pragma unroll
      for (int n = 0; n < 4; ++n) acc[m][n] = (f32x4)0.f;

    int ra = tid >> 2;
    int fsa = (tid & 3) * 16;
    int rb = tid >> 1;
    int fsb = (tid & 1) * 32;

    const float* bpA = basis + ((size_t)(i0g + ra) * 9 + t) * FD_ + fsa;
    const short* mpA = mag_bf + ((size_t)b * CI_ + i0g + ra) * FD_ + fsa;
    const short* opB = olbf + (size_t)rb * FD_ + fsb;

    for (int cc = 0; cc < 8; ++cc) {
      int f0 = cc * 64;
      __syncthreads();
#pragma unroll
      for (int u = 0; u < 2; ++u) {
        s16x8 m8 = *(const s16x8*)(mpA + f0 + u * 8);
        s16x8 pk;
#pragma unroll
        for (int j = 0; j < 2; ++j) {
          float4 b4 = *(const float4*)(bpA + f0 + u * 8 + j * 4);
          pk[j * 4 + 0] = f2bf(b4.x * bf2f(m8[j * 4 + 0]));
          pk[j * 4 + 1] = f2bf(b4.y * bf2f(m8[j * 4 + 1]));
          pk[j * 4 + 2] = f2bf(b4.z * bf2f(m8[j * 4 + 2]));
          pk[j * 4 + 3] = f2bf(b4.w * bf2f(m8[j * 4 + 3]));
        }
        int slot = (tid & 3) * 2 + u;
        *(s16x8*)&alds[ra * 64 + ((slot ^ (ra & 7)) << 3)] = pk;
      }
#pragma unroll
      for (int u = 0; u < 4; ++u) {
        s16x8 pk = *(const s16x8*)(opB + f0 + u * 8);
        int slot = (tid & 1) * 4 + u;
        *(s16x8*)&blds[rb * 64 + ((slot ^ (rb & 7)) << 3)] = pk;
      }
      __syncthreads();

#pragma unroll
      for (int ks = 0; ks < 2; ++ks) {
        bf16x8 afr[4], bfr[4];
#pragma unroll
        for (int m = 0; m < 4; ++m) {
          int row = wm * 64 + m * 16 + l15;
          int slot = ks * 4 + kb;
          afr[m] = *(const bf16x8*)&alds[row * 64 + ((slot ^ (row & 7)) << 3)];
        }
#pragma unroll
        for (int n = 0; n < 4; ++n) {
          int row = wn * 64 + n * 16 + l15;
          int slot = ks * 4 + kb;
          bfr[n] = *(const bf16x8*)&blds[row * 64 + ((slot ^ (row & 7)) << 3)];
        }
#pragma unroll
        for (int m = 0; m < 4; ++m)
#pragma unroll
          for (int n = 0; n < 4; ++n)
            acc[m][n] = __builtin_amdgcn_mfma_f32_16x16x32_bf16(afr[m], bfr[n], acc[m][n], 0, 0, 0);
      }
    }

    const float KSCALE = 1.0f / 1536.0f;
#pragma unroll
    for (int m = 0; m < 4; ++m) {
      int i_loc = i0g + wm * 64 + m * 16 + (lane >> 4) * 4;
      int kb2 = (i_loc >> 3) & 3;
      int cc2 = i_loc >> 5;
      int e2  = i_loc & 7;
#pragma unroll
      for (int n = 0; n < 4; ++n) {
        int o = wn * 64 + n * 16 + l15;
        short4 s4;
        s4.x = f2bf(acc[m][n][0] * KSCALE);
        s4.y = f2bf(acc[m][n][1] * KSCALE);
        s4.z = f2bf(acc[m][n][2] * KSCALE);
        s4.w = f2bf(acc[m][n][3] * KSCALE);
        *(short4*)(kbf + koff(b, kb2, cc2, t, o) + e2) = s4;
      }
    }
  } else {
    // ================= xpose: 2 rows per block =================
    float* lx2 = (float*)smem_s;
    int bid = blockIdx.x - 288;
    int b = bid / 33, pr = bid - b * 33;
    int half = tid >> 8;
    int t2 = tid & 255;
    int hp = pr * 2 + half;
    bool interior = (hp >= 1 && hp <= 64);
    int h = hp - 1;
    const float* xb = x + ((size_t)b * CI_) * H_ * W_ + (size_t)h * W_;
    float* lx = lx2 + half * 2048;
    s16x8 z = (s16x8)0;
    int w = t2 >> 2, kb = t2 & 3;

    for (int cc = 0; cc < 8; ++cc) {
      __syncthreads();
      if (interior) {
        int rr = t2 >> 4, c4 = (t2 & 15) * 4;
        *(float4*)&lx[rr * 64 + c4] =
            *(const float4*)(xb + (size_t)(cc * 32 + rr) * H_ * W_ + c4);
        *(float4*)&lx[(rr + 16) * 64 + c4] =
            *(const float4*)(xb + (size_t)(cc * 32 + rr + 16) * H_ * W_ + c4);
      }
      __syncthreads();
      if (interior) {
        s16x8 o8;
#pragma unroll
        for (int k2 = 0; k2 < 8; ++k2) o8[k2] = f2bf(lx[(kb * 8 + k2) * 64 + w]);
        *(s16x8*)(xt + xoff(b, kb, cc, hp, w + 1)) = o8;
        if (w == 0) {
          *(s16x8*)(xt + xoff(b, kb, cc, hp, 0)) = z;
          *(s16x8*)(xt + xoff(b, kb, cc, hp, 65)) = z;
        }
      } else {
        for (int e = t2; e < 264; e += 256) {
          int kb2 = e / 66, wp = e - kb2 * 66;
          *(s16x8*)(xt + xoff(b, kb2, cc, hp, wp)) = z;
        }
      }
    }
  }
}

// ---------------------------------------------------------------- conv via MFMA (barrier-free, wave-private staging)
// block: (b, 64-o tile, 4-row tile); 4 waves; wave = 64 o x 64 px (one row).
// NO __syncthreads in the cc loop: each wave stages its OWN 3-halo-row X
// working set (13 KB, disjoint LDS region) via global_load_lds, then a
// wave-private s_waitcnt vmcnt(0) + sched_barrier. Waves drift into
// independent phases -> stage latency of one wave is covered by MFMA of
// others (no block-wide convoy). A-frags inline from L2 (proven text).
__global__ __launch_bounds__(256, 3) void conv_mfma_kernel(
    const short* __restrict__ xt, const short* __restrict__ kbf,
    const float* __restrict__ conv_bias, float* __restrict__ out) {
  int bid = ((blockIdx.x & 7) << 7) + (blockIdx.x >> 3);  // bijective, 1024 = 8*128
  int b  = bid >> 6;
  int ot = (bid >> 4) & 3;
  int rt = bid & 15;
  int o_base = ot * 64;
  int r0 = rt * 4;
  int tid = threadIdx.x;
  int lane = tid & 63;
  int wv = tid >> 6;
  int orow = lane & 15, kb = lane >> 4;

  // per-wave region: [kb 4][3 rows][66 wp][8 ci] = 792 slots, padded to 832 (13 KB)
  __shared__ short xs[4 * 6656];    // 53,248 B total

  f32x4 acc[4][4];
#pragma unroll
  for (int m = 0; m < 4; ++m)
#pragma unroll
    for (int n = 0; n < 4; ++n) acc[m][n] = (f32x4)0.f;

  // lane-constant A base; frag addr = abase + cc*18432 + t*2048 + m*128
  const short* abase = kbf + koff(b, kb, 0, 0, o_base + orow);
  short* xw = &xs[wv * 6656];

  for (int cc = 0; cc < 8; ++cc) {
    // ---- stage this wave's 3 rows (hp = r0+wv+{0,1,2}), 13 x 1KB chunks
    for (int ch = 0; ch < 13; ++ch) {
      int s = ch * 64 + lane;
      s = s < 792 ? s : 791;
      int kb2 = s / 198;
      int rem = s - kb2 * 198;
      int r = rem / 66;
      int c = rem - r * 66;
      const short* src = xt + xoff(b, kb2, cc, r0 + wv + r, c);
      gload16(src, &xw[ch * 512]);
    }
    // wave-private drain: no block barrier
    asm volatile("s_waitcnt vmcnt(0)" ::: "memory");
    __builtin_amdgcn_sched_barrier(0);

    const short* ac = abase + (size_t)cc * 18432;
#pragma unroll
    for (int t = 0; t < 9; ++t) {
      const int dh = t / 3 - 1, dw = t % 3 - 1;
      bf16x8 afr[4], bfr[4];
#pragma unroll
      for (int m = 0; m < 4; ++m)
        afr[m] = *(const bf16x8*)(ac + t * 2048 + m * 128);
#pragma unroll
      for (int n = 0; n < 4; ++n) {
        int xc = n * 16 + orow + 1 + dw;
        bfr[n] = *(const bf16x8*)&xw[(kb * 198 + (1 + dh) * 66 + xc) * 8];
      }
#pragma unroll
      for (int m = 0; m < 4; ++m)
#pragma unroll
        for (int n = 0; n < 4; ++n)
          acc[m][n] = __builtin_amdgcn_mfma_f32_16x16x32_bf16(afr[m], bfr[n], acc[m][n], 0, 0, 0);
    }
  }

  // ---- epilogue: silu + bias
  int row = r0 + wv;
#pragma unroll
  for (int m = 0; m < 4; ++m) {
#pragma unroll
    for (int q = 0; q < 4; ++q) {
      int o = o_base + m * 16 + (lane >> 4) * 4 + q;
      float bias = conv_bias[o];
      size_t obase = (((size_t)b * CO_ + o) * H_ + row) * W_;
#pragma unroll
      for (int n = 0; n < 4; ++n) {
        float y = acc[m][n][q];
        out[obase + n * 16 + (lane & 15)] = y / (1.f + __expf(-y)) + bias;
      }
    }
  }
}

extern "C" void kernel_launch(void* const* d_in, const int* in_sizes, int n_in,
                              void* d_out, int out_size, void* d_ws, size_t ws_size,
                              hipStream_t stream) {
  const float* x          = (const float*)d_in[0];
  const float* temb       = (const float*)d_in[1];
  const float* basis      = (const float*)d_in[2];
  const float* magnitude  = (const float*)d_in[3];
  const float* out_linear = (const float*)d_in[4];
  const float* affine_w   = (const float*)d_in[5];
  const float* affine_b   = (const float*)d_in[6];
  const float* conv_bias  = (const float*)d_in[7];
  float* out = (float*)d_out;

  char* ws = (char*)d_ws;
  float* s_ws = (float*)ws;                          // 1 KB
  short* kbf  = (short*)(ws + 1024);                 // 18.9 MB
  short* xt   = (short*)(ws + 1024 + 18874368);      // 35.7 MB
  short* mag_bf = (short*)(ws + 1024 + 18874368 + 35684352);  // 4 MB
  short* olbf   = (short*)(ws + 1024 + 18874368 + 35684352 + 4194304);  // 256 KB

  prep_kernel<<<65, 256, 0, stream>>>(temb, affine_w, affine_b, out_linear, s_ws, olbf);
  magmix_kernel<<<512, 256, 0, stream>>>(magnitude, s_ws, mag_bf);
  synth_xpose_kernel<<<816, 512, 0, stream>>>(basis, mag_bf, olbf, kbf, x, xt);
  conv_mfma_kernel<<<1024, 256, 0, stream>>>(xt, kbf, conv_bias, out);
}

// Round 19
// 135.982 us; speedup vs baseline: 1.2888x; 1.2888x over previous
//
#include <hip/hip_runtime.h>
#include <hip/hip_bf16.h>
#include <math.h>

#define B_    16
#define CI_   256
#define CO_   256
#define H_    64
#define W_    64
#define WDIM_ 512
#define NF_   16
#define FD_   512

typedef short bf16x8 __attribute__((ext_vector_type(8)));
typedef short s16x8  __attribute__((ext_vector_type(8)));
typedef float f32x4  __attribute__((ext_vector_type(4)));

__device__ __forceinline__ short f2bf(float f) {
  union { float f; unsigned u; } x; x.f = f;
  unsigned r = (x.u + 0x7FFFu + ((x.u >> 16) & 1u)) >> 16;
  return (short)r;
}
__device__ __forceinline__ float bf2f(short s) {
  union { unsigned u; float f; } x; x.u = ((unsigned)(unsigned short)s) << 16;
  return x.f;
}

__device__ __forceinline__ void gload16(const short* g, short* l) {
  __builtin_amdgcn_global_load_lds(
      (const __attribute__((address_space(1))) void*)g,
      (__attribute__((address_space(3))) void*)l, 16, 0, 0);
}

// Slice-major global layouts (elements):
//   kbf: [b][kb 4][cc 8][t 9][o 256][e 8]
//   xt : [b][kb 4][cc 8][hp 66][wp 66][e 8]
__device__ __forceinline__ size_t koff(int b, int kb, int cc, int t, int o) {
  return ((((((size_t)b * 4 + kb) * 8 + cc) * 9 + t) * 256) + o) * 8;
}
__device__ __forceinline__ size_t xoff(int b, int kb, int cc, int hp, int wp) {
  return ((((((size_t)b * 4 + kb) * 8 + cc) * 66 + hp) * 66) + wp) * 8;
}

// ---------------------------------------------------------------- prep: affine + out_linear->bf16
__global__ __launch_bounds__(256) void prep_kernel(
    const float* __restrict__ temb, const float* __restrict__ affine_w,
    const float* __restrict__ affine_b, const float* __restrict__ out_linear,
    float* __restrict__ s_ws, short* __restrict__ olbf) {
  int tid = threadIdx.x;
  if (blockIdx.x == 0) {
    int b = tid >> 4, k = tid & 15;
    const float* t = temb + b * WDIM_;
    const float* w = affine_w + k * WDIM_;
    float acc = 0.f;
    for (int j = 0; j < WDIM_; j += 4) {
      float4 tv = *(const float4*)(t + j);
      float4 wv = *(const float4*)(w + j);
      acc += tv.x * wv.x + tv.y * wv.y + tv.z * wv.z + tv.w * wv.w;
    }
    const float WGAIN = 6.9053399e-4f;  // (1/64)/sqrt(512)
    const float LRM   = 1.0f / 64.0f;
    s_ws[tid] = acc * WGAIN + affine_b[k] * LRM;
  } else {
    int e = (blockIdx.x - 1) * 256 + tid;   // vec8 index, 16384 total
    const float* src = out_linear + (size_t)e * 8;
    s16x8 pk;
#pragma unroll
    for (int j = 0; j < 8; ++j) pk[j] = f2bf(src[j]);
    *(s16x8*)(olbf + (size_t)e * 8) = pk;
  }
}

// ---------------------------------------------------------------- mag mix (per-i blocks)
__global__ __launch_bounds__(256) void magmix_kernel(
    const float* __restrict__ magnitude, const float* __restrict__ s_ws,
    short* __restrict__ mag_bf) {
  int bid = blockIdx.x;
  int i = bid >> 1;
  int f = ((bid & 1) << 8) + threadIdx.x;
  __shared__ float ssh[256];
  ssh[threadIdx.x] = s_ws[threadIdx.x];
  __syncthreads();
  float mg[16];
#pragma unroll
  for (int k = 0; k < 16; ++k)
    mg[k] = magnitude[(size_t)(k * CI_ + i) * FD_ + f];
#pragma unroll
  for (int b = 0; b < 16; ++b) {
    float acc = 0.f;
#pragma unroll
    for (int k = 0; k < 16; ++k) acc += mg[k] * ssh[b * 16 + k];
    mag_bf[(size_t)(b * CI_ + i) * FD_ + f] = f2bf(acc * 0.25f);
  }
}

// ---------------------------------------------------------------- fused kernsynth (MFMA) + xpose (HBM)
// blocks [0,288): kernsynth, block = (b, t, i-half), 512 thr = 8 waves
// blocks [288,816): xpose, block = (b, row-pair), 512 thr = 2 rows x 256
__global__ __launch_bounds__(512) void synth_xpose_kernel(
    const float* __restrict__ basis, const short* __restrict__ mag_bf,
    const short* __restrict__ olbf, short* __restrict__ kbf,
    const float* __restrict__ x, short* __restrict__ xt) {
  __shared__ short smem_s[24576];   // 48 KB union
  int tid = threadIdx.x;

  if (blockIdx.x < 288) {
    // ================= kernsynth =================
    short* alds = smem_s;           // [i 128][f 64] swizzled, 16 KB
    short* blds = smem_s + 8192;    // [o 256][f 64] swizzled, 32 KB
    int bid = blockIdx.x;
    int b  = bid / 18;
    int mt = bid - b * 18;
    int t   = mt >> 1;
    int i0g = (mt & 1) * 128;

    int lane = tid & 63;
    int wv = tid >> 6;
    int wm = wv >> 2, wn = wv & 3;
    int l15 = lane & 15, kb = lane >> 4;

    f32x4 acc[4][4];
#pragma unroll
    for (int m = 0; m < 4; ++m)
#pragma unroll
      for (int n = 0; n < 4; ++n) acc[m][n] = (f32x4)0.f;

    int ra = tid >> 2;              // A row (i offset), 0..127
    int fsa = (tid & 3) * 16;       // A f-seg base (16 f)
    int rb = tid >> 1;              // B row (o), 0..255
    int fsb = (tid & 1) * 32;       // B f-seg base (32 f)

    const float* bpA = basis + ((size_t)(i0g + ra) * 9 + t) * FD_ + fsa;
    const short* mpA = mag_bf + ((size_t)b * CI_ + i0g + ra) * FD_ + fsa;
    const short* opB = olbf + (size_t)rb * FD_ + fsb;

    for (int cc = 0; cc < 8; ++cc) {
      int f0 = cc * 64;
      __syncthreads();
#pragma unroll
      for (int u = 0; u < 2; ++u) {
        s16x8 m8 = *(const s16x8*)(mpA + f0 + u * 8);
        s16x8 pk;
#pragma unroll
        for (int j = 0; j < 2; ++j) {
          float4 b4 = *(const float4*)(bpA + f0 + u * 8 + j * 4);
          pk[j * 4 + 0] = f2bf(b4.x * bf2f(m8[j * 4 + 0]));
          pk[j * 4 + 1] = f2bf(b4.y * bf2f(m8[j * 4 + 1]));
          pk[j * 4 + 2] = f2bf(b4.z * bf2f(m8[j * 4 + 2]));
          pk[j * 4 + 3] = f2bf(b4.w * bf2f(m8[j * 4 + 3]));
        }
        int slot = (tid & 3) * 2 + u;
        *(s16x8*)&alds[ra * 64 + ((slot ^ (ra & 7)) << 3)] = pk;
      }
#pragma unroll
      for (int u = 0; u < 4; ++u) {
        s16x8 pk = *(const s16x8*)(opB + f0 + u * 8);
        int slot = (tid & 1) * 4 + u;
        *(s16x8*)&blds[rb * 64 + ((slot ^ (rb & 7)) << 3)] = pk;
      }
      __syncthreads();

#pragma unroll
      for (int ks = 0; ks < 2; ++ks) {
        bf16x8 afr[4], bfr[4];
#pragma unroll
        for (int m = 0; m < 4; ++m) {
          int row = wm * 64 + m * 16 + l15;
          int slot = ks * 4 + kb;
          afr[m] = *(const bf16x8*)&alds[row * 64 + ((slot ^ (row & 7)) << 3)];
        }
#pragma unroll
        for (int n = 0; n < 4; ++n) {
          int row = wn * 64 + n * 16 + l15;
          int slot = ks * 4 + kb;
          bfr[n] = *(const bf16x8*)&blds[row * 64 + ((slot ^ (row & 7)) << 3)];
        }
#pragma unroll
        for (int m = 0; m < 4; ++m)
#pragma unroll
          for (int n = 0; n < 4; ++n)
            acc[m][n] = __builtin_amdgcn_mfma_f32_16x16x32_bf16(afr[m], bfr[n], acc[m][n], 0, 0, 0);
      }
    }

    const float KSCALE = 1.0f / 1536.0f;  // FREQ_GAIN * GAIN
#pragma unroll
    for (int m = 0; m < 4; ++m) {
      int i_loc = i0g + wm * 64 + m * 16 + (lane >> 4) * 4;
      int kb2 = (i_loc >> 3) & 3;
      int cc2 = i_loc >> 5;
      int e2  = i_loc & 7;
#pragma unroll
      for (int n = 0; n < 4; ++n) {
        int o = wn * 64 + n * 16 + l15;
        short4 s4;
        s4.x = f2bf(acc[m][n][0] * KSCALE);
        s4.y = f2bf(acc[m][n][1] * KSCALE);
        s4.z = f2bf(acc[m][n][2] * KSCALE);
        s4.w = f2bf(acc[m][n][3] * KSCALE);
        *(short4*)(kbf + koff(b, kb2, cc2, t, o) + e2) = s4;
      }
    }
  } else {
    // ================= xpose: 2 rows per block =================
    float* lx2 = (float*)smem_s;          // [2][32*64] = 16 KB
    int bid = blockIdx.x - 288;           // 0..527
    int b = bid / 33, pr = bid - b * 33;  // row-pair 0..32
    int half = tid >> 8;
    int t2 = tid & 255;
    int hp = pr * 2 + half;               // 0..65
    bool interior = (hp >= 1 && hp <= 64);
    int h = hp - 1;
    const float* xb = x + ((size_t)b * CI_) * H_ * W_ + (size_t)h * W_;
    float* lx = lx2 + half * 2048;
    s16x8 z = (s16x8)0;
    int w = t2 >> 2, kb = t2 & 3;

    for (int cc = 0; cc < 8; ++cc) {
      __syncthreads();
      if (interior) {
        int rr = t2 >> 4, c4 = (t2 & 15) * 4;
        *(float4*)&lx[rr * 64 + c4] =
            *(const float4*)(xb + (size_t)(cc * 32 + rr) * H_ * W_ + c4);
        *(float4*)&lx[(rr + 16) * 64 + c4] =
            *(const float4*)(xb + (size_t)(cc * 32 + rr + 16) * H_ * W_ + c4);
      }
      __syncthreads();
      if (interior) {
        s16x8 o8;
#pragma unroll
        for (int k2 = 0; k2 < 8; ++k2) o8[k2] = f2bf(lx[(kb * 8 + k2) * 64 + w]);
        *(s16x8*)(xt + xoff(b, kb, cc, hp, w + 1)) = o8;
        if (w == 0) {   // edge columns
          *(s16x8*)(xt + xoff(b, kb, cc, hp, 0)) = z;
          *(s16x8*)(xt + xoff(b, kb, cc, hp, 65)) = z;
        }
      } else {
        for (int e = t2; e < 264; e += 256) {
          int kb2 = e / 66, wp = e - kb2 * 66;
          *(s16x8*)(xt + xoff(b, kb2, cc, hp, wp)) = z;
        }
      }
    }
  }
}

// ---------------------------------------------------------------- conv via MFMA (R11/R12-proven exact text)
// block: (b, 64-o tile, 4-row tile); 4 waves; wave = 64 o x 64 px (one row).
// A-frags direct from global kbf (L2-resident, contiguous 256B per 16-lane
// group) -> VMEM pipe. X staged in LDS (25 KB, slice-major, conflict-free).
// XCD-chunked bid swizzle. Staging address math stays INSIDE the cc-loop
// (hoisting it regressed +65% — compiler issue-schedule sensitivity).
__global__ __launch_bounds__(256, 4) void conv_mfma_kernel(
    const short* __restrict__ xt, const short* __restrict__ kbf,
    const float* __restrict__ conv_bias, float* __restrict__ out) {
  int bid = ((blockIdx.x & 7) << 7) + (blockIdx.x >> 3);  // bijective, 1024 = 8*128
  int b  = bid >> 6;
  int ot = (bid >> 4) & 3;
  int rt = bid & 15;
  int o_base = ot * 64;
  int r0 = rt * 4;
  int tid = threadIdx.x;
  int lane = tid & 63;
  int wv = tid >> 6;
  int orow = lane & 15, kb = lane >> 4;

  __shared__ short xs[25 * 512];    // 25,600 B  [kb][400 px-slots][8]

  f32x4 acc[4][4];
#pragma unroll
  for (int m = 0; m < 4; ++m)
#pragma unroll
    for (int n = 0; n < 4; ++n) acc[m][n] = (f32x4)0.f;

  // lane-constant A base; frag addr = abase + cc*18432 + t*2048 + m*128
  const short* abase = kbf + koff(b, kb, 0, 0, o_base + orow);

  for (int cc = 0; cc < 8; ++cc) {
    __syncthreads();  // all waves done reading previous chunk
    // ---- X: 25 x 1KB chunks; slice-major, 6400B per kb-slice (400 slots, 396 used)
    for (int ch = wv; ch < 25; ch += 4) {
      int D = ch * 1024 + lane * 16;
      int kb2 = D / 6400;
      int r = (D - kb2 * 6400) >> 4;
      r = r < 396 ? r : 395;
      int xr = (r * 1986) >> 17;   // r / 66
      int c = r - xr * 66;
      const short* src = xt + xoff(b, kb2, cc, r0 + xr, c);
      gload16(src, &xs[ch * 512]);
    }
    __syncthreads();

    const short* ac = abase + (size_t)cc * 18432;
#pragma unroll
    for (int t = 0; t < 9; ++t) {
      const int dh = t / 3 - 1, dw = t % 3 - 1;
      bf16x8 afr[4], bfr[4];
#pragma unroll
      for (int m = 0; m < 4; ++m)
        afr[m] = *(const bf16x8*)(ac + t * 2048 + m * 128);
      int xr = wv + 1 + dh;
#pragma unroll
      for (int n = 0; n < 4; ++n) {
        int xc = n * 16 + orow + 1 + dw;
        bfr[n] = *(const bf16x8*)&xs[(kb * 400 + xr * 66 + xc) * 8];
      }
#pragma unroll
      for (int m = 0; m < 4; ++m)
#pragma unroll
        for (int n = 0; n < 4; ++n)
          acc[m][n] = __builtin_amdgcn_mfma_f32_16x16x32_bf16(afr[m], bfr[n], acc[m][n], 0, 0, 0);
    }
  }

  // ---- epilogue: silu + bias
  int row = r0 + wv;
#pragma unroll
  for (int m = 0; m < 4; ++m) {
#pragma unroll
    for (int q = 0; q < 4; ++q) {
      int o = o_base + m * 16 + (lane >> 4) * 4 + q;
      float bias = conv_bias[o];
      size_t obase = (((size_t)b * CO_ + o) * H_ + row) * W_;
#pragma unroll
      for (int n = 0; n < 4; ++n) {
        float y = acc[m][n][q];
        out[obase + n * 16 + (lane & 15)] = y / (1.f + __expf(-y)) + bias;
      }
    }
  }
}

extern "C" void kernel_launch(void* const* d_in, const int* in_sizes, int n_in,
                              void* d_out, int out_size, void* d_ws, size_t ws_size,
                              hipStream_t stream) {
  const float* x          = (const float*)d_in[0];
  const float* temb       = (const float*)d_in[1];
  const float* basis      = (const float*)d_in[2];
  const float* magnitude  = (const float*)d_in[3];
  const float* out_linear = (const float*)d_in[4];
  const float* affine_w   = (const float*)d_in[5];
  const float* affine_b   = (const float*)d_in[6];
  const float* conv_bias  = (const float*)d_in[7];
  float* out = (float*)d_out;

  char* ws = (char*)d_ws;
  float* s_ws = (float*)ws;                          // 1 KB
  short* kbf  = (short*)(ws + 1024);                 // 18.9 MB
  short* xt   = (short*)(ws + 1024 + 18874368);      // 35.7 MB
  // mag_bf (4 MB) and olbf (256 KB) follow xt
  short* mag_bf = (short*)(ws + 1024 + 18874368 + 35684352);
  short* olbf   = (short*)(ws + 1024 + 18874368 + 35684352 + 4194304);

  prep_kernel<<<65, 256, 0, stream>>>(temb, affine_w, affine_b, out_linear, s_ws, olbf);
  magmix_kernel<<<512, 256, 0, stream>>>(magnitude, s_ws, mag_bf);
  synth_xpose_kernel<<<816, 512, 0, stream>>>(basis, mag_bf, olbf, kbf, x, xt);
  conv_mfma_kernel<<<1024, 256, 0, stream>>>(xt, kbf, conv_bias, out);
}